// Round 4
// baseline (705.296 us; speedup 1.0000x reference)
//
#include <hip/hip_runtime.h>

#define S_LEN 2048
#define D_MODEL 4096
#define N_HEADS 32
#define N_KV 8
#define HEAD_DIM 128

typedef float f32x4 __attribute__((ext_vector_type(4)));
typedef short bf16x8 __attribute__((ext_vector_type(8)));

__device__ __forceinline__ unsigned short f2bf(float f) {
  unsigned int u = __float_as_uint(f);
  unsigned int r = (u + 0x7fffu + ((u >> 16) & 1u)) >> 16;
  return (unsigned short)r;
}
__device__ __forceinline__ float bf2f(unsigned short b) {
  return __uint_as_float(((unsigned int)b) << 16);
}
__device__ __forceinline__ void gload_lds16(const void* g, void* l) {
  __builtin_amdgcn_global_load_lds((const __attribute__((address_space(1))) void*)g,
                                   (__attribute__((address_space(3))) void*)l, 16, 0, 0);
}

// ---------------- f32 -> bf16 convert (vectorized, grid-stride) ----------------
__global__ void cvt_f32_bf16(const float* __restrict__ in, unsigned short* __restrict__ out, int n4) {
  int stride = gridDim.x * blockDim.x;
  for (int i = blockIdx.x * blockDim.x + threadIdx.x; i < n4; i += stride) {
    float4 v = ((const float4*)in)[i];
    unsigned int lo = (unsigned int)f2bf(v.x) | ((unsigned int)f2bf(v.y) << 16);
    unsigned int hi = (unsigned int)f2bf(v.z) | ((unsigned int)f2bf(v.w) << 16);
    uint2 o; o.x = lo; o.y = hi;
    ((uint2*)out)[i] = o;
  }
}

// ---------------- f32 K x N  ->  bf16 N x K (transpose + convert) ----------------
__global__ void transpose_cvt(const float* __restrict__ in, unsigned short* __restrict__ out,
                              int K, int N) {
  __shared__ float tile[32][33];
  int k0 = blockIdx.y << 5, n0 = blockIdx.x << 5;
  int tx = threadIdx.x, ty = threadIdx.y;
#pragma unroll
  for (int r = 0; r < 32; r += 8)
    tile[ty + r][tx] = in[(k0 + ty + r) * N + n0 + tx];
  __syncthreads();
#pragma unroll
  for (int r = 0; r < 32; r += 8)
    out[(n0 + ty + r) * K + k0 + tx] = f2bf(tile[tx][ty + r]);
}

// ---------------- bf16 transpose: out[c][r] = in[r][col0 + c] ----------------
__global__ void transpose_bf16(const unsigned short* __restrict__ in, unsigned short* __restrict__ out,
                               int inStride, int outStride, int col0) {
  __shared__ unsigned short tile[32][33];
  int r0 = blockIdx.y << 5, c0 = blockIdx.x << 5;
  int tx = threadIdx.x, ty = threadIdx.y;
#pragma unroll
  for (int r = 0; r < 32; r += 8)
    tile[ty + r][tx] = in[(r0 + ty + r) * inStride + col0 + c0 + tx];
  __syncthreads();
#pragma unroll
  for (int r = 0; r < 32; r += 8)
    out[(c0 + ty + r) * outStride + r0 + tx] = tile[tx][ty + r];
}

// ---------------- in-place RoPE on bf16 [S][rowStride], pairs (2p, 2p+1) per head ----------------
__global__ void rope_k(unsigned short* __restrict__ t, const float* __restrict__ cb,
                       const float* __restrict__ sb, int rowStride, int shift) {
  int idx = blockIdx.x * blockDim.x + threadIdx.x;
  int pos = idx >> shift;
  int wp = idx & ((1 << shift) - 1);
  int p = wp & 63;
  int col = ((wp >> 6) << 7) + (p << 1);
  unsigned int* addr = (unsigned int*)&t[pos * rowStride + col];
  unsigned int pr = *addr;
  float t0 = bf2f((unsigned short)(pr & 0xffffu));
  float t1 = bf2f((unsigned short)(pr >> 16));
  float c = cb[pos * 64 + p], s = sb[pos * 64 + p];
  float o0 = t0 * c - t1 * s;
  float o1 = t0 * s + t1 * c;
  *addr = (unsigned int)f2bf(o0) | ((unsigned int)f2bf(o1) << 16);
}

// ---------------- GEMM: C[M x N] = A[M x K] * Bt[N x K]^T   (bf16 in, f32 acc) ----------------
__device__ __forceinline__ void store_out(unsigned short* p, float v) { *p = f2bf(v); }
__device__ __forceinline__ void store_out(float* p, float v) { *p = v; }

template <typename OT>
__global__ __launch_bounds__(256, 2) void gemm_bt(const unsigned short* __restrict__ A,
                                                  const unsigned short* __restrict__ Bt,
                                                  OT* __restrict__ C, int M, int N, int K) {
  __shared__ __align__(16) unsigned short As[128 * 32];
  __shared__ __align__(16) unsigned short Bs[128 * 32];
  const int tid = threadIdx.x;
  const int w = tid >> 6, l = tid & 63;
  const int lrow = l & 15, lk = l >> 4;
  const int m0 = blockIdx.y * 128, n0 = blockIdx.x * 128;
  const int wm = (w >> 1) * 64, wn = (w & 1) * 64;
  f32x4 acc[4][4] = {};

  for (int kt = 0; kt < K; kt += 32) {
    __syncthreads();
#pragma unroll
    for (int p = 0; p < 2; ++p) {
      int e = (p * 256 + tid) * 8;
      int r = e >> 5, c = e & 31;
      gload_lds16(&A[(m0 + r) * K + kt + c], (char*)As + p * 4096 + w * 1024);
      gload_lds16(&Bt[(n0 + r) * K + kt + c], (char*)Bs + p * 4096 + w * 1024);
    }
    __syncthreads();
    bf16x8 af[4], bfr[4];
#pragma unroll
    for (int i = 0; i < 4; ++i)
      af[i] = *(const bf16x8*)&As[(wm + i * 16 + lrow) * 32 + lk * 8];
#pragma unroll
    for (int j = 0; j < 4; ++j)
      bfr[j] = *(const bf16x8*)&Bs[(wn + j * 16 + lrow) * 32 + lk * 8];
#pragma unroll
    for (int i = 0; i < 4; ++i)
#pragma unroll
      for (int j = 0; j < 4; ++j)
        acc[i][j] = __builtin_amdgcn_mfma_f32_16x16x32_bf16(af[i], bfr[j], acc[i][j], 0, 0, 0);
  }
#pragma unroll
  for (int i = 0; i < 4; ++i)
#pragma unroll
    for (int j = 0; j < 4; ++j)
#pragma unroll
      for (int r = 0; r < 4; ++r) {
        int row = m0 + wm + i * 16 + lk * 4 + r;
        int col = n0 + wn + j * 16 + lrow;
        store_out(&C[row * N + col], acc[i][j][r]);
      }
}

// ---------------- causal GQA flash attention (no-staging, wave-independent) ----------------
// grid: 512 x 256thr. Each WAVE owns (32 q-rows, head). K/V read directly from
// global (L1/L2-resident: 4MB total; 4 waves/block share one GQA group's K/V).
// No __syncthreads in the whole kernel; only wave-local LDS for P.
__global__ __launch_bounds__(256, 2) void attn_fwd(const unsigned short* __restrict__ Q,
                                                   const unsigned short* __restrict__ Kb,
                                                   const unsigned short* __restrict__ Vt,
                                                   unsigned short* __restrict__ Ctx) {
  __shared__ __align__(16) unsigned short Ps[4][32 * 72];  // per-wave P, pad 72

  const int tid = threadIdx.x, w = tid >> 6, l = tid & 63;
  const int lrow = l & 15, lk = l >> 4;
  const int gw = blockIdx.x * 4 + w;       // 0..2047 wave tasks
  const int qh = gw & 31;                  // head (block groups 4 heads = 1 GQA group)
  const int qc = 63 - (gw >> 5);           // q-chunk, heavy (high q) first
  const int wq0 = qc * 32;
  const int g = qh >> 2;                   // kv head
  // scale * log2(e): softmax computed in exp2 domain
  const float scale2 = 0.12751879f;

  // Q fragments in registers for the whole loop
  bf16x8 qf[2][4];
#pragma unroll
  for (int i = 0; i < 2; ++i)
#pragma unroll
    for (int ks = 0; ks < 4; ++ks)
      qf[i][ks] = *(const bf16x8*)&Q[(wq0 + i * 16 + lrow) * D_MODEL + qh * HEAD_DIM + ks * 32 + lk * 8];

  f32x4 o[2][8] = {};
  float mrun[2][4], lrun[2][4], al[2][4];
#pragma unroll
  for (int i = 0; i < 2; ++i)
#pragma unroll
    for (int r = 0; r < 4; ++r) { mrun[i][r] = -1e30f; lrun[i][r] = 0.0f; }

  const int nt = (wq0 + 95) >> 6;  // ceil((wq0+32)/64)
  for (int t = 0; t < nt; ++t) {
    const int kv0 = t << 6;
    const bool last = (t == nt - 1);  // only the diagonal tile needs masking

    // S = Q K^T  (32 x 64), K fragments straight from global (L1/L2 hit)
    f32x4 sa[2][4] = {};
#pragma unroll
    for (int ks = 0; ks < 4; ++ks) {
      bf16x8 kf[4];
#pragma unroll
      for (int j = 0; j < 4; ++j)
        kf[j] = *(const bf16x8*)&Kb[(kv0 + j * 16 + lrow) * 2048 + g * HEAD_DIM + ks * 32 + lk * 8];
#pragma unroll
      for (int i = 0; i < 2; ++i)
#pragma unroll
        for (int j = 0; j < 4; ++j)
          sa[i][j] = __builtin_amdgcn_mfma_f32_16x16x32_bf16(qf[i][ks], kf[j], sa[i][j], 0, 0, 0);
    }

    // online softmax in exp2 domain (rows spread over 16-lane groups)
#pragma unroll
    for (int i = 0; i < 2; ++i)
#pragma unroll
      for (int r = 0; r < 4; ++r) {
        float sv[4];
        float mx = -1e30f;
        if (last) {
          int qrow = wq0 + i * 16 + lk * 4 + r;
#pragma unroll
          for (int j = 0; j < 4; ++j) {
            float x = sa[i][j][r] * scale2;
            int kvcol = kv0 + j * 16 + lrow;
            if (kvcol > qrow) x = -1e30f;
            sv[j] = x;
            mx = fmaxf(mx, x);
          }
        } else {
#pragma unroll
          for (int j = 0; j < 4; ++j) {
            float x = sa[i][j][r] * scale2;
            sv[j] = x;
            mx = fmaxf(mx, x);
          }
        }
#pragma unroll
        for (int d = 1; d < 16; d <<= 1) mx = fmaxf(mx, __shfl_xor(mx, d));
        float mold = mrun[i][r];
        float mnew = fmaxf(mold, mx);
        float alpha = __builtin_exp2f(mold - mnew);
        float rs = 0.0f;
        float ps[4];
#pragma unroll
        for (int j = 0; j < 4; ++j) { ps[j] = __builtin_exp2f(sv[j] - mnew); rs += ps[j]; }
#pragma unroll
        for (int d = 1; d < 16; d <<= 1) rs += __shfl_xor(rs, d);
        mrun[i][r] = mnew;
        lrun[i][r] = lrun[i][r] * alpha + rs;
        al[i][r] = alpha;
#pragma unroll
        for (int j = 0; j < 4; ++j)
          Ps[w][(i * 16 + lk * 4 + r) * 72 + j * 16 + lrow] = f2bf(ps[j]);
      }

    // rescale O
#pragma unroll
    for (int i = 0; i < 2; ++i)
#pragma unroll
      for (int n = 0; n < 8; ++n)
#pragma unroll
        for (int r = 0; r < 4; ++r) o[i][n][r] *= al[i][r];

    // O += P V   (P via wave-local LDS; V^T fragments straight from global)
#pragma unroll
    for (int ks = 0; ks < 2; ++ks) {
      bf16x8 pa[2];
#pragma unroll
      for (int i = 0; i < 2; ++i)
        pa[i] = *(const bf16x8*)&Ps[w][(i * 16 + lrow) * 72 + ks * 32 + lk * 8];
#pragma unroll
      for (int n = 0; n < 8; ++n) {
        bf16x8 vf = *(const bf16x8*)&Vt[(g * HEAD_DIM + n * 16 + lrow) * 2048 + kv0 + ks * 32 + lk * 8];
#pragma unroll
        for (int i = 0; i < 2; ++i)
          o[i][n] = __builtin_amdgcn_mfma_f32_16x16x32_bf16(pa[i], vf, o[i][n], 0, 0, 0);
      }
    }
  }

  // epilogue: O / l  -> ctx (bf16)
#pragma unroll
  for (int i = 0; i < 2; ++i) {
    float inv[4];
#pragma unroll
    for (int r = 0; r < 4; ++r) inv[r] = 1.0f / lrun[i][r];
#pragma unroll
    for (int n = 0; n < 8; ++n)
#pragma unroll
      for (int r = 0; r < 4; ++r) {
        int row = wq0 + i * 16 + lk * 4 + r;
        int col = n * 16 + lrow;
        Ctx[row * D_MODEL + qh * HEAD_DIM + col] = f2bf(o[i][n][r] * inv[r]);
      }
  }
}

// ---------------- host launch ----------------
extern "C" void kernel_launch(void* const* d_in, const int* in_sizes, int n_in,
                              void* d_out, int out_size, void* d_ws, size_t ws_size,
                              hipStream_t stream) {
  const float* x = (const float*)d_in[0];
  const float* wq = (const float*)d_in[1];
  const float* wk = (const float*)d_in[2];
  const float* wv = (const float*)d_in[3];
  const float* wo = (const float*)d_in[4];
  const float* fcos = (const float*)d_in[5];
  const float* fsin = (const float*)d_in[6];
  float* out = (float*)d_out;

  char* ws = (char*)d_ws;
  unsigned short* xb = (unsigned short*)ws;                      // 16MB: x bf16; later ctx
  unsigned short* ctx = xb;
  unsigned short* wt = (unsigned short*)(ws + (size_t)16 * 1024 * 1024);   // 32MB weights^T
  unsigned short* qb = (unsigned short*)(ws + (size_t)48 * 1024 * 1024);   // 16MB Q
  unsigned short* kvb = (unsigned short*)(ws + (size_t)64 * 1024 * 1024);  // 8MB K|V [2048][2048]
  unsigned short* vtg = (unsigned short*)(ws + (size_t)72 * 1024 * 1024);  // 4MB V^T [1024][2048]

  // x -> bf16
  cvt_f32_bf16<<<2048, 256, 0, stream>>>(x, xb, S_LEN * D_MODEL / 4);

  // Q = x @ wq
  transpose_cvt<<<dim3(128, 128), dim3(32, 8), 0, stream>>>(wq, wt, 4096, 4096);
  gemm_bt<unsigned short><<<dim3(32, 16), 256, 0, stream>>>(xb, wt, qb, S_LEN, 4096, 4096);

  // K|V = x @ [wk|wv]  (fused, N=2048)
  transpose_cvt<<<dim3(32, 128), dim3(32, 8), 0, stream>>>(wk, wt, 4096, 1024);
  transpose_cvt<<<dim3(32, 128), dim3(32, 8), 0, stream>>>(wv, wt + (size_t)1024 * 4096, 4096, 1024);
  gemm_bt<unsigned short><<<dim3(16, 16), 256, 0, stream>>>(xb, wt, kvb, S_LEN, 2048, 4096);

  // RoPE in-place on Q and K
  rope_k<<<(S_LEN * 2048) / 256, 256, 0, stream>>>(qb, fcos, fsin, 4096, 11);
  rope_k<<<(S_LEN * 512) / 256, 256, 0, stream>>>(kvb, fcos, fsin, 2048, 9);

  // V^T in global: vtg[c][r] = kvb[r][1024 + c]
  transpose_bf16<<<dim3(32, 64), dim3(32, 8), 0, stream>>>(kvb, vtg, 2048, 2048, 1024);

  // attention (wave-per-task, no staging)
  attn_fwd<<<dim3(512), 256, 0, stream>>>(qb, kvb, vtg, ctx);

  // out = ctx @ wo  (f32 output)
  transpose_cvt<<<dim3(128, 128), dim3(32, 8), 0, stream>>>(wo, wt, 4096, 4096);
  gemm_bt<float><<<dim3(32, 16), 256, 0, stream>>>(ctx, wt, out, S_LEN, 4096, 4096);
}